// Round 8
// baseline (101.794 us; speedup 1.0000x reference)
//
#include <hip/hip_runtime.h>

// LateralEI: out = GAIN * rownorm(K) @ h, K = 0.8*exp(-d2/0.72) - exp(-d2/2.88)
// z: [8192][2] f32, h: [8192][128] f32, out: [8192][128] f32
//
// R8: isolation experiment. R4/R6/R7 all pinned at main~41us across three
// structures (2w/SIMD regs, 2w/SIMD ring, 4w/SIMD ring+barriers) => either
// occupancy was never the fix (per-CU limiter) or R7's barrier lockstep ate
// the TLP gain. R8 = R4's barrier-free per-wave structure AT 4 waves/SIMD:
// no LDS, no barriers, no DMA, no manual vmcnt anywhere in main. Per wave:
// 32 rows x 512-k slice; per iter 8 coalesced B-loads (single-buffered; the
// ~350cyc w-production is the latency cover), 4 quad-uniform z-loads,
// 16 w's, 16 MFMAs. launch_bounds(256,4) caps 128 regs (est. ~126).

typedef float f32x4 __attribute__((ext_vector_type(4)));
typedef short s16x8 __attribute__((ext_vector_type(8)));
typedef unsigned int u32x4 __attribute__((ext_vector_type(4)));

#define NPTS 8192
#define DH 128
#define A_I (-0.5009357781f)  // -log2(e)/(2*1.2^2); A_E = 4*A_I
#define GAIN_C 0.05f

#define NKS 16      // cross-block K-slices (512 k each)
#define KSL 512
#define NITER 16    // 512 / 32
#define NRT 64      // row-tiles (128 rows = 4 waves x 32)

// ---------- pre-pass: h [8192][128] f32 -> hTf fragment-major bf16 (R4-verified) ----------
// Fragment (k5=k>>5, cf): 512 halfwords at hTf[(k5*8+cf)*512]; chunk for lane
// (q=lane>>4, nf=lane&15) at +lane*8 holds h[k5*32+q*8+j][cf*16+nf], j=0..7.
__global__ __launch_bounds__(256) void h_to_hTf(
    const float* __restrict__ h, unsigned short* __restrict__ hTf) {
  __shared__ unsigned int tileW[DH * 17];  // [n][kp], kp = k-pair 0..15
  const int t = threadIdx.x;
  const int k5 = blockIdx.x;
  const int n = t & 127;
  const int g = t >> 7;  // 0..1
#pragma unroll
  for (int p = 0; p < 8; ++p) {
    const int kp = g * 8 + p;
    unsigned int a = __float_as_uint(h[(k5 * 32 + 2 * kp) * DH + n]);
    unsigned int b = __float_as_uint(h[(k5 * 32 + 2 * kp + 1) * DH + n]);
    a = (a + 0x7fffu + ((a >> 16) & 1u)) >> 16;          // RNE low half
    b = (b + 0x7fffu + ((b >> 16) & 1u)) & 0xffff0000u;  // RNE high half
    tileW[n * 17 + kp] = a | b;
  }
  __syncthreads();
#pragma unroll
  for (int it = 0; it < 2; ++it) {
    const int u = t + it * 256;
    const int cf = u >> 6;
    const int lane = u & 63;
    const int nf = lane & 15;
    const int q = lane >> 4;
    const int n2 = cf * 16 + nf;
    u32x4 val;
#pragma unroll
    for (int i = 0; i < 4; ++i) val[i] = tileW[n2 * 17 + q * 4 + i];
    *(u32x4*)(hTf + k5 * 4096 + u * 8) = val;
  }
}

// ---------- main fused kernel: fully independent waves, zero sync ----------
__global__ __launch_bounds__(256, 4) void lateral_ei_main(
    const float* __restrict__ z, const unsigned short* __restrict__ hTf,
    unsigned short* __restrict__ partb, float* __restrict__ prs) {
  const int t = threadIdx.x;
  const int lane = t & 63;
  const int w = t >> 6;  // wave 0..3
  const int rt = blockIdx.x & (NRT - 1);
  const int ks = blockIdx.x >> 6;  // 0..NKS-1
  const int i0 = rt * 128 + w * 32;
  const int nf = lane & 15;
  const int q = lane >> 4;
  const int k0 = ks * KSL;

  // zi constants for rows i0+nf, i0+16+nf
  const float zx0 = z[(i0 + nf) * 2], zy0 = z[(i0 + nf) * 2 + 1];
  const float zx1 = z[(i0 + 16 + nf) * 2], zy1 = z[(i0 + 16 + nf) * 2 + 1];
  const float cA0 = A_I * (zx0 * zx0 + zy0 * zy0);
  const float cA1 = A_I * (zx1 * zx1 + zy1 * zy1);
  const float cX0 = -2.f * A_I * zx0, cY0 = -2.f * A_I * zy0;
  const float cX1 = -2.f * A_I * zx1, cY1 = -2.f * A_I * zy1;

  // B base for this wave's k-slice: fragment (ks*16+it, cf), lane chunk
  const unsigned short* hb = hTf + (size_t)(ks * 16) * 4096 + lane * 8;
  // z base for this lane's 8 k's per iter (quad-uniform across 16 lanes)
  const float* zj = z + (size_t)(k0 + q * 8) * 2;

  f32x4 acc0[8], acc1[8];
#pragma unroll
  for (int cf = 0; cf < 8; ++cf) {
    acc0[cf] = (f32x4){0.f, 0.f, 0.f, 0.f};
    acc1[cf] = (f32x4){0.f, 0.f, 0.f, 0.f};
  }
  float rs0a = 0.f, rs0b = 0.f, rs1a = 0.f, rs1b = 0.f;

#pragma unroll 1
  for (int it = 0; it < NITER; ++it) {
    // ---- issue 8 coalesced B-loads first (in flight across w-production)
    s16x8 bfr[8];
#pragma unroll
    for (int cf = 0; cf < 8; ++cf)
      bfr[cf] = *(const s16x8*)(hb + it * 4096 + cf * 512);

    // ---- z for this iter's 8 k's (quad-uniform 16B loads, L1-hot)
    const f32x4 zcA = *(const f32x4*)(zj + it * 64 + 0);
    const f32x4 zcB = *(const f32x4*)(zj + it * 64 + 4);
    const f32x4 zcC = *(const f32x4*)(zj + it * 64 + 8);
    const f32x4 zcD = *(const f32x4*)(zj + it * 64 + 12);

    // ---- 16 w's (az inline via m2; verified math path)
    float wv0[8], wv1[8];
#pragma unroll
    for (int j = 0; j < 8; ++j) {
      const f32x4 zp = (j < 2) ? zcA : (j < 4) ? zcB : (j < 6) ? zcC : zcD;
      const float xj = zp[(j & 1) * 2], yj = zp[(j & 1) * 2 + 1];
      const float m2 = fmaf(yj, yj, xj * xj);
      const float u0 = fmaf(cX0, xj, fmaf(cY0, yj, fmaf(A_I, m2, cA0)));
      const float u1 = fmaf(cX1, xj, fmaf(cY1, yj, fmaf(A_I, m2, cA1)));
      const float ei0 = __builtin_amdgcn_exp2f(u0);
      const float ei1 = __builtin_amdgcn_exp2f(u1);
      const float s0 = ei0 * ei0, s1 = ei1 * ei1;
      const float w0 = fmaf(0.8f, s0 * s0, -ei0);  // e_E = e_I^4
      const float w1 = fmaf(0.8f, s1 * s1, -ei1);
      wv0[j] = w0; wv1[j] = w1;
      if (j & 1) { rs0b += w0; rs1b += w1; } else { rs0a += w0; rs1a += w1; }
    }
    union { unsigned int u[4]; s16x8 v; } af0, af1;
#pragma unroll
    for (int p = 0; p < 4; ++p) {
      af0.u[p] = __builtin_amdgcn_perm(__float_as_uint(wv0[2 * p + 1]),
                                       __float_as_uint(wv0[2 * p]), 0x07060302);
      af1.u[p] = __builtin_amdgcn_perm(__float_as_uint(wv1[2 * p + 1]),
                                       __float_as_uint(wv1[2 * p]), 0x07060302);
    }
    const s16x8 a0 = af0.v, a1 = af1.v;

    // ---- 16 MFMAs (compiler inserts the vmcnt waits for bfr here)
#pragma unroll
    for (int cf = 0; cf < 8; ++cf) {
      acc0[cf] = __builtin_amdgcn_mfma_f32_16x16x32_bf16(a0, bfr[cf], acc0[cf], 0, 0, 0);
      acc1[cf] = __builtin_amdgcn_mfma_f32_16x16x32_bf16(a1, bfr[cf], acc1[cf], 0, 0, 0);
    }
  }

  // ---- rowsum: sum 4 quad-partials per row (lanes nf,nf+16,nf+32,nf+48)
  float rs0 = rs0a + rs0b, rs1 = rs1a + rs1b;
  rs0 += __shfl_xor(rs0, 16);
  rs0 += __shfl_xor(rs0, 32);
  rs1 += __shfl_xor(rs1, 16);
  rs1 += __shfl_xor(rs1, 32);
  if (lane < 16) {
    prs[ks * NPTS + i0 + nf] = rs0;
    prs[ks * NPTS + i0 + 16 + nf] = rs1;
  }

  // ---- partial store, bf16 RNE (C/D layout: col=cf*16+nf, row=q*4+r)
  unsigned short* pb = partb + (size_t)ks * (NPTS * DH);
#pragma unroll
  for (int cf = 0; cf < 8; ++cf)
#pragma unroll
    for (int r = 0; r < 4; ++r) {
      unsigned int u0 = __float_as_uint(acc0[cf][r]);
      unsigned int u1 = __float_as_uint(acc1[cf][r]);
      u0 = (u0 + 0x7fffu + ((u0 >> 16) & 1u)) >> 16;
      u1 = (u1 + 0x7fffu + ((u1 >> 16) & 1u)) >> 16;
      pb[(i0 + q * 4 + r) * DH + cf * 16 + nf] = (unsigned short)u0;
      pb[(i0 + 16 + q * 4 + r) * DH + cf * 16 + nf] = (unsigned short)u1;
    }
}

// ---------- reduce NKS K-slice partials + normalize + scale ----------
__global__ __launch_bounds__(256) void reduce_scale(
    const unsigned short* __restrict__ partb, const float* __restrict__ prs,
    float* __restrict__ out) {
  const int gid = blockIdx.x * 256 + threadIdx.x;  // 8 cols each
  const int base = gid * 8;
  const int row = gid >> 4;
  float c[8] = {0.f, 0.f, 0.f, 0.f, 0.f, 0.f, 0.f, 0.f};
  float rsum = 0.f;
#pragma unroll
  for (int s = 0; s < NKS; ++s) {
    const u32x4 v = *(const u32x4*)(partb + (size_t)s * (NPTS * DH) + base);
#pragma unroll
    for (int i = 0; i < 4; ++i) {
      c[2 * i] += __uint_as_float(v[i] << 16);
      c[2 * i + 1] += __uint_as_float(v[i] & 0xffff0000u);
    }
    rsum += prs[s * NPTS + row];
  }
  const float scl = GAIN_C / (rsum + 1e-6f);
  f32x4 o0 = {c[0] * scl, c[1] * scl, c[2] * scl, c[3] * scl};
  f32x4 o1 = {c[4] * scl, c[5] * scl, c[6] * scl, c[7] * scl};
  *(f32x4*)(out + base) = o0;
  *(f32x4*)(out + base + 4) = o1;
}

extern "C" void kernel_launch(void* const* d_in, const int* in_sizes, int n_in,
                              void* d_out, int out_size, void* d_ws, size_t ws_size,
                              hipStream_t stream) {
  (void)in_sizes; (void)n_in; (void)out_size; (void)ws_size;
  const float* z = (const float*)d_in[0];
  const float* h = (const float*)d_in[1];
  float* out = (float*)d_out;
  unsigned short* hTf = (unsigned short*)d_ws;                          // 2 MiB
  unsigned short* partb = (unsigned short*)((char*)d_ws + (2u << 20));  // 32 MiB bf16
  float* prs = (float*)((char*)d_ws + (34u << 20));                     // 512 KiB

  h_to_hTf<<<NPTS / 32, 256, 0, stream>>>(h, hTf);
  lateral_ei_main<<<NRT * NKS, 256, 0, stream>>>(z, hTf, partb, prs);
  reduce_scale<<<(NPTS * DH / 8) / 256, 256, 0, stream>>>(partb, prs, out);
}